// Round 10
// baseline (603.832 us; speedup 1.0000x reference)
//
#include <hip/hip_runtime.h>
#include <math.h>

#define BB 4
#define NN 512
#define CS 384
#define CP 128
#define NBIN 65
#define NRBF 32
#define GT 2048      // table resolution over d in [0,1]
#define JT 64        // j-tile per block in main kernel

typedef float nf4 __attribute__((ext_vector_type(4)));

// ---------------- Kernel A: PI = s@W_i + (b_i+b_rel+b_t), PJ = s@W_j + b_j ----
// grid (256, 2), block 256. 8 rows per block; thread = (rr = tid>>5, c4 = tid&31).
__global__ __launch_bounds__(256) void proj_kernel(
    const float* __restrict__ s,
    const float* __restrict__ Wi, const float* __restrict__ Wj,
    const float* __restrict__ bi, const float* __restrict__ bj,
    const float* __restrict__ brel, const float* __restrict__ bt,
    float* __restrict__ PI, float* __restrict__ PJ)
{
    __shared__ float s_lds[8 * CS];   // 12 KB
    const int row0 = blockIdx.x * 8;

    // stage 8 contiguous rows of s (8*384 = 3072 floats = 768 float4)
    const float4* src = (const float4*)(s + (size_t)row0 * CS);
    float4* dst = (float4*)s_lds;
    #pragma unroll
    for (int p = 0; p < 3; ++p) dst[threadIdx.x + p * 256] = src[threadIdx.x + p * 256];
    __syncthreads();

    const int rr = threadIdx.x >> 5;
    const int c4 = threadIdx.x & 31;
    const int isJ = blockIdx.y;

    const float4* W4 = (const float4*)(isJ ? Wj : Wi);
    float4 acc;
    if (!isJ) {
        float4 b0 = ((const float4*)bi)[c4];
        float4 b1 = ((const float4*)brel)[c4];
        float4 b2 = ((const float4*)bt)[c4];
        acc = make_float4(b0.x + b1.x + b2.x, b0.y + b1.y + b2.y,
                          b0.z + b1.z + b2.z, b0.w + b1.w + b2.w);
    } else {
        acc = ((const float4*)bj)[c4];
    }

    const float* srow = s_lds + rr * CS;
    #pragma unroll 4
    for (int k = 0; k < CS; k += 4) {
        float4 sv = *(const float4*)(srow + k);
        float4 w0 = W4[(k + 0) * 32 + c4];
        float4 w1 = W4[(k + 1) * 32 + c4];
        float4 w2 = W4[(k + 2) * 32 + c4];
        float4 w3 = W4[(k + 3) * 32 + c4];
        acc.x += sv.x * w0.x; acc.y += sv.x * w0.y; acc.z += sv.x * w0.z; acc.w += sv.x * w0.w;
        acc.x += sv.y * w1.x; acc.y += sv.y * w1.y; acc.z += sv.y * w1.z; acc.w += sv.y * w1.w;
        acc.x += sv.z * w2.x; acc.y += sv.z * w2.y; acc.z += sv.z * w2.z; acc.w += sv.z * w2.w;
        acc.x += sv.w * w3.x; acc.y += sv.w * w3.y; acc.z += sv.w * w3.z; acc.w += sv.w * w3.w;
    }

    float4* out4 = (float4*)(isJ ? PJ : PI);
    out4[(size_t)(row0 + rr) * 32 + c4] = acc;
}

// ---------------- Kernel B: F[g][c] = cut(d_g) * sum_r rbf_r(d_g) * W_t[r][c] --
// grid GT, block 128.
__global__ void table_kernel(const float* __restrict__ Wt, float* __restrict__ F)
{
    const int g = blockIdx.x;
    const int c = threadIdx.x;
    const float d = (float)g * (1.0f / (float)(GT - 1));
    const float e = expf(-d);
    const float cut = 0.5f * (cosf((float)M_PI * d * 0.2f) + 1.0f);  // d < 5 always here
    const float m0 = expf(-5.0f);
    const float dm = (1.0f - m0) / (float)(NRBF - 1);
    const double bd = 0.0625 * (1.0 - exp(-5.0));
    const float beta = (float)(1.0 / (bd * bd));
    float acc = 0.0f;
    #pragma unroll
    for (int r = 0; r < NRBF; ++r) {
        float u = e - (m0 + (float)r * dm);
        acc += expf(-beta * u * u) * Wt[r * CP + c];
    }
    F[g * CP + c] = cut * acc;
}

// ---------------- Kernel C: main pair kernel --------------------------------
// grid (NN/JT, NN, BB), block 256. thread = (jlane = tid>>5, c4 = tid&31).
__global__ __launch_bounds__(256) void pair_kernel(
    const float* __restrict__ t, const float* __restrict__ r,
    const float* __restrict__ mask, const float* __restrict__ Wrel,
    const float* __restrict__ PI, const float* __restrict__ PJ,
    const float* __restrict__ F, float* __restrict__ out)
{
    __shared__ int   kk[JT];   // table float4-row offset (k*32)
    __shared__ float fr[JT];   // lerp fraction
    __shared__ float mm[JT];   // pair mask
    __shared__ int   wb[JT];   // Wrel float4 offset (bucket*32)

    const int b  = blockIdx.z;
    const int i  = blockIdx.y;
    const int j0 = blockIdx.x * JT;
    const int bi = b * NN + i;

    if (threadIdx.x < JT) {
        const int jj = threadIdx.x;
        const int j  = j0 + jj;
        const float ri = r[bi];
        const float rj = r[b * NN + j];
        const float mi = mask[bi];
        const float mj = mask[b * NN + j];
        const float tv = t[(size_t)bi * NN + j];
        float x = fminf(fmaxf(tv, 0.0f), 1.0f);
        float pos = x * (float)(GT - 1);
        int k = (int)pos;
        if (k > GT - 2) k = GT - 2;
        fr[jj] = pos - (float)k;
        kk[jj] = k * 32;
        float diff = rintf(ri - rj);
        diff = fminf(fmaxf(diff, -32.0f), 32.0f);
        wb[jj] = ((int)diff + 32) * 32;
        mm[jj] = mi * mj;
    }
    __syncthreads();

    const int c4    = threadIdx.x & 31;
    const int jlane = threadIdx.x >> 5;

    const float4 pi = ((const float4*)PI)[(size_t)bi * 32 + c4];
    const float4* __restrict__ PJ4 = (const float4*)PJ + (size_t)(b * NN + j0) * 32;
    const float4* __restrict__ F4  = (const float4*)F;
    const float4* __restrict__ WR4 = (const float4*)Wrel;
    nf4* __restrict__ O4 = (nf4*)out + ((size_t)bi * NN + j0) * 32;

    #pragma unroll
    for (int it = 0; it < JT / 8; ++it) {
        const int jj = jlane + it * 8;
        const int k  = kk[jj];
        const float f = fr[jj];
        const float m = mm[jj];
        const int wo = wb[jj];
        float4 pj = PJ4[(size_t)jj * 32 + c4];
        float4 wr = WR4[wo + c4];
        float4 t0 = F4[k + c4];
        float4 t1 = F4[k + 32 + c4];
        nf4 v;
        v.x = (pi.x + pj.x + wr.x + t0.x + (t1.x - t0.x) * f) * m;
        v.y = (pi.y + pj.y + wr.y + t0.y + (t1.y - t0.y) * f) * m;
        v.z = (pi.z + pj.z + wr.z + t0.z + (t1.z - t0.z) * f) * m;
        v.w = (pi.w + pj.w + wr.w + t0.w + (t1.w - t0.w) * f) * m;
        __builtin_nontemporal_store(v, &O4[(size_t)jj * 32 + c4]);
    }
}

extern "C" void kernel_launch(void* const* d_in, const int* in_sizes, int n_in,
                              void* d_out, int out_size, void* d_ws, size_t ws_size,
                              hipStream_t stream) {
    const float* s    = (const float*)d_in[0];
    const float* t    = (const float*)d_in[1];
    const float* r    = (const float*)d_in[2];
    const float* mask = (const float*)d_in[3];
    const float* Wi   = (const float*)d_in[4];
    const float* bi   = (const float*)d_in[5];
    const float* Wj   = (const float*)d_in[6];
    const float* bj   = (const float*)d_in[7];
    const float* Wrel = (const float*)d_in[8];
    const float* brel = (const float*)d_in[9];
    const float* Wt   = (const float*)d_in[10];
    const float* bt   = (const float*)d_in[11];
    float* out = (float*)d_out;

    char* ws = (char*)d_ws;
    float* PI = (float*)(ws);                    // 2048*128*4 = 1 MiB
    float* PJ = (float*)(ws + (1u << 20));       // 1 MiB
    float* F  = (float*)(ws + (2u << 20));       // GT*128*4 = 1 MiB

    hipLaunchKernelGGL(proj_kernel, dim3(256, 2), dim3(256), 0, stream,
                       s, Wi, Wj, bi, bj, brel, bt, PI, PJ);
    hipLaunchKernelGGL(table_kernel, dim3(GT), dim3(CP), 0, stream, Wt, F);
    hipLaunchKernelGGL(pair_kernel, dim3(NN / JT, NN, BB), dim3(256), 0, stream,
                       t, r, mask, Wrel, PI, PJ, F, out);
}

// Round 12
// 581.610 us; speedup vs baseline: 1.0382x; 1.0382x over previous
//
#include <hip/hip_runtime.h>
#include <math.h>

#define BB 4
#define NN 512
#define CS 384
#define CP 128
#define NBIN 65
#define NRBF 32
#define GT 4096      // table resolution over d in [0,1]; nearest-neighbor lookup
#define JT 64        // j-tile per block in main kernel

typedef float nf4 __attribute__((ext_vector_type(4)));

// ---------------- Kernel A: PI = s@W_i + (b_i+b_rel+b_t), PJ = s@W_j + b_j ----
// grid (256, 2), block 256. 8 rows per block; thread = (rr = tid>>5, c4 = tid&31).
__global__ __launch_bounds__(256) void proj_kernel(
    const float* __restrict__ s,
    const float* __restrict__ Wi, const float* __restrict__ Wj,
    const float* __restrict__ bi, const float* __restrict__ bj,
    const float* __restrict__ brel, const float* __restrict__ bt,
    float* __restrict__ PI, float* __restrict__ PJ)
{
    __shared__ float s_lds[8 * CS];   // 12 KB
    const int row0 = blockIdx.x * 8;

    // stage 8 contiguous rows of s (8*384 = 3072 floats = 768 float4)
    const float4* src = (const float4*)(s + (size_t)row0 * CS);
    float4* dst = (float4*)s_lds;
    #pragma unroll
    for (int p = 0; p < 3; ++p) dst[threadIdx.x + p * 256] = src[threadIdx.x + p * 256];
    __syncthreads();

    const int rr = threadIdx.x >> 5;
    const int c4 = threadIdx.x & 31;
    const int isJ = blockIdx.y;

    const float4* W4 = (const float4*)(isJ ? Wj : Wi);
    float4 acc;
    if (!isJ) {
        float4 b0 = ((const float4*)bi)[c4];
        float4 b1 = ((const float4*)brel)[c4];
        float4 b2 = ((const float4*)bt)[c4];
        acc = make_float4(b0.x + b1.x + b2.x, b0.y + b1.y + b2.y,
                          b0.z + b1.z + b2.z, b0.w + b1.w + b2.w);
    } else {
        acc = ((const float4*)bj)[c4];
    }

    const float* srow = s_lds + rr * CS;
    #pragma unroll 4
    for (int k = 0; k < CS; k += 4) {
        float4 sv = *(const float4*)(srow + k);
        float4 w0 = W4[(k + 0) * 32 + c4];
        float4 w1 = W4[(k + 1) * 32 + c4];
        float4 w2 = W4[(k + 2) * 32 + c4];
        float4 w3 = W4[(k + 3) * 32 + c4];
        acc.x += sv.x * w0.x; acc.y += sv.x * w0.y; acc.z += sv.x * w0.z; acc.w += sv.x * w0.w;
        acc.x += sv.y * w1.x; acc.y += sv.y * w1.y; acc.z += sv.y * w1.z; acc.w += sv.y * w1.w;
        acc.x += sv.z * w2.x; acc.y += sv.z * w2.y; acc.z += sv.z * w2.z; acc.w += sv.z * w2.w;
        acc.x += sv.w * w3.x; acc.y += sv.w * w3.y; acc.z += sv.w * w3.z; acc.w += sv.w * w3.w;
    }

    float4* out4 = (float4*)(isJ ? PJ : PI);
    out4[(size_t)(row0 + rr) * 32 + c4] = acc;
}

// ---------------- Kernel B: F[g][c] = cut(d_g) * sum_r rbf_r(d_g) * W_t[r][c] --
// grid GT, block 128.
__global__ void table_kernel(const float* __restrict__ Wt, float* __restrict__ F)
{
    const int g = blockIdx.x;
    const int c = threadIdx.x;
    const float d = (float)g * (1.0f / (float)(GT - 1));
    const float e = expf(-d);
    const float cut = 0.5f * (cosf((float)M_PI * d * 0.2f) + 1.0f);  // d < 5 always here
    const float m0 = expf(-5.0f);
    const float dm = (1.0f - m0) / (float)(NRBF - 1);
    const double bd = 0.0625 * (1.0 - exp(-5.0));
    const float beta = (float)(1.0 / (bd * bd));
    float acc = 0.0f;
    #pragma unroll
    for (int r = 0; r < NRBF; ++r) {
        float u = e - (m0 + (float)r * dm);
        acc += expf(-beta * u * u) * Wt[r * CP + c];
    }
    F[g * CP + c] = cut * acc;
}

// ---------------- Kernel C: main pair kernel --------------------------------
// grid (NN/JT, NN, BB), block 256. thread = (jlane = tid>>5, c4 = tid&31).
// Nearest-neighbor table lookup (GT=4096): one F load per output float4.
__global__ __launch_bounds__(256) void pair_kernel(
    const float* __restrict__ t, const float* __restrict__ r,
    const float* __restrict__ mask, const float* __restrict__ Wrel,
    const float* __restrict__ PI, const float* __restrict__ PJ,
    const float* __restrict__ F, float* __restrict__ out)
{
    __shared__ int   kk[JT];   // table float4-row offset (k*32)
    __shared__ float mm[JT];   // pair mask
    __shared__ int   wb[JT];   // Wrel float4 offset (bucket*32)

    const int b  = blockIdx.z;
    const int i  = blockIdx.y;
    const int j0 = blockIdx.x * JT;
    const int bi = b * NN + i;

    if (threadIdx.x < JT) {
        const int jj = threadIdx.x;
        const int j  = j0 + jj;
        const float ri = r[bi];
        const float rj = r[b * NN + j];
        const float mi = mask[bi];
        const float mj = mask[b * NN + j];
        const float tv = t[(size_t)bi * NN + j];
        float x = fminf(fmaxf(tv, 0.0f), 1.0f);
        int k = (int)(x * (float)(GT - 1) + 0.5f);
        if (k > GT - 1) k = GT - 1;
        kk[jj] = k * 32;
        float diff = rintf(ri - rj);
        diff = fminf(fmaxf(diff, -32.0f), 32.0f);
        wb[jj] = ((int)diff + 32) * 32;
        mm[jj] = mi * mj;
    }
    __syncthreads();

    const int c4    = threadIdx.x & 31;
    const int jlane = threadIdx.x >> 5;

    const float4 pi = ((const float4*)PI)[(size_t)bi * 32 + c4];
    const float4* __restrict__ PJ4 = (const float4*)PJ + (size_t)(b * NN + j0) * 32;
    const float4* __restrict__ F4  = (const float4*)F;
    const float4* __restrict__ WR4 = (const float4*)Wrel;
    nf4* __restrict__ O4 = (nf4*)out + ((size_t)bi * NN + j0) * 32;

    #pragma unroll
    for (int it = 0; it < JT / 8; ++it) {
        const int jj = jlane + it * 8;
        const int k  = kk[jj];
        const float m = mm[jj];
        const int wo = wb[jj];
        float4 pj = PJ4[(size_t)jj * 32 + c4];
        float4 wr = WR4[wo + c4];
        float4 t0 = F4[k + c4];
        nf4 v;
        v.x = (pi.x + pj.x + wr.x + t0.x) * m;
        v.y = (pi.y + pj.y + wr.y + t0.y) * m;
        v.z = (pi.z + pj.z + wr.z + t0.z) * m;
        v.w = (pi.w + pj.w + wr.w + t0.w) * m;
        __builtin_nontemporal_store(v, &O4[(size_t)jj * 32 + c4]);
    }
}

extern "C" void kernel_launch(void* const* d_in, const int* in_sizes, int n_in,
                              void* d_out, int out_size, void* d_ws, size_t ws_size,
                              hipStream_t stream) {
    const float* s    = (const float*)d_in[0];
    const float* t    = (const float*)d_in[1];
    const float* r    = (const float*)d_in[2];
    const float* mask = (const float*)d_in[3];
    const float* Wi   = (const float*)d_in[4];
    const float* bi   = (const float*)d_in[5];
    const float* Wj   = (const float*)d_in[6];
    const float* bj   = (const float*)d_in[7];
    const float* Wrel = (const float*)d_in[8];
    const float* brel = (const float*)d_in[9];
    const float* Wt   = (const float*)d_in[10];
    const float* bt   = (const float*)d_in[11];
    float* out = (float*)d_out;

    char* ws = (char*)d_ws;
    float* PI = (float*)(ws);                    // 2048*128*4 = 1 MiB
    float* PJ = (float*)(ws + (1u << 20));       // 1 MiB
    float* F  = (float*)(ws + (2u << 20));       // GT*128*4 = 2 MiB

    hipLaunchKernelGGL(proj_kernel, dim3(256, 2), dim3(256), 0, stream,
                       s, Wi, Wj, bi, bj, brel, bt, PI, PJ);
    hipLaunchKernelGGL(table_kernel, dim3(GT), dim3(CP), 0, stream, Wt, F);
    hipLaunchKernelGGL(pair_kernel, dim3(NN / JT, NN, BB), dim3(256), 0, stream,
                       t, r, mask, Wrel, PI, PJ, F, out);
}